// Round 5
// baseline (1111.913 us; speedup 1.0000x reference)
//
#include <hip/hip_runtime.h>
#include <hip/hip_fp16.h>
#include <cstdint>
#include <cstddef>

// ---------------------------------------------------------------------------
// GCNClassifier: 3x (GCNConv + tanh) + linear head, N=100k nodes, E=3.2M edges
// Round 14: src-chunked pull with register-persistent accumulators.
//  - bucket_build sorts each row by src (LDS insertion sort) and emits
//    rsC[c][v] = start of chunk-c subrange (chunk = src>>13: 2MB Hs1 slice
//    per chunk < 4MB per-XCD L2).
//  - pull_chunk: persistent grid (782 blocks), acc for 8 (L1) / 4 (L2) nodes
//    in registers across the chunk-pass loop; all resident blocks sweep the
//    same chunk -> gathers become L2 hits. Col read ONCE (fixes round-11's
//    8x re-read); node TLP unchanged (16 lanes/node).
//  - gemm path, CSR pipeline, pull_cls unchanged from round 12.
// ---------------------------------------------------------------------------

#define EPB 16384        // edges per hist/scatter chunk
#define BSHIFT 8         // bucket = dst >> 8 (256 dst nodes per bucket)
#define NBUC_MAX 512     // 100000>>8 = 390 max bucket id
#define BCAP 12800       // bucket_build LDS edge capacity (avg 8192, 50+ sigma)
#define CSH 13           // src-chunk shift: 8192 nodes/chunk

typedef __attribute__((ext_vector_type(8))) short short8;
typedef __attribute__((ext_vector_type(4))) float f32x4;

// --- generic two-level exclusive scan ---
__global__ __launch_bounds__(256) void scan_block(const int* __restrict__ src, int n,
                                                  int* __restrict__ incl,
                                                  int* __restrict__ bsum) {
    int tid = threadIdx.x;
    int v = blockIdx.x * 256 + tid;
    int val = (v < n) ? src[v] : 0;
    int lane = tid & 63, w = tid >> 6;
#pragma unroll
    for (int off = 1; off < 64; off <<= 1) {
        int t = __shfl_up(val, off, 64);
        if (lane >= off) val += t;
    }
    __shared__ int wsum[4];
    if (lane == 63) wsum[w] = val;
    __syncthreads();
#pragma unroll
    for (int i = 0; i < 4; ++i)
        if (i < w) val += wsum[i];
    if (v < n) incl[v] = val;
    if (tid == 255) bsum[blockIdx.x] = val;
}

__global__ __launch_bounds__(512) void scan_sums(int* __restrict__ bsum, int nb) {
    int tid = threadIdx.x;              // nb <= 512
    int val = (tid < nb) ? bsum[tid] : 0;
    int lane = tid & 63, w = tid >> 6;
#pragma unroll
    for (int off = 1; off < 64; off <<= 1) {
        int t = __shfl_up(val, off, 64);
        if (lane >= off) val += t;
    }
    __shared__ int wsum[8];
    if (lane == 63) wsum[w] = val;
    __syncthreads();
#pragma unroll
    for (int i = 0; i < 8; ++i)
        if (i < w) val += wsum[i];
    if (tid < nb) bsum[tid] = val;
}

__global__ __launch_bounds__(256) void finalize_scan(
    const int* __restrict__ incl, const int* __restrict__ bsum,
    const int* __restrict__ src, int n, int* __restrict__ excl) {
    int v = blockIdx.x * 256 + threadIdx.x;
    if (v >= n) return;
    int boff = (blockIdx.x == 0) ? 0 : bsum[blockIdx.x - 1];
    excl[v] = boff + incl[v] - src[v];
}

// Pass A: per-chunk histogram over dst buckets (LDS atomics only).
__global__ __launch_bounds__(256) void hist_bucket(
    const int* __restrict__ ei, int E, int nbuc, int nch,
    int* __restrict__ histG) {
    __shared__ int h[NBUC_MAX];
    const int k = blockIdx.x;
    for (int b = threadIdx.x; b < NBUC_MAX; b += 256) h[b] = 0;
    __syncthreads();
    const int base = k * EPB, end = min(E, base + EPB);
    for (int i = base + threadIdx.x; i < end; i += 256)
        atomicAdd(&h[ei[(size_t)E + i] >> BSHIFT], 1);
    __syncthreads();
    for (int b = threadIdx.x; b < nbuc; b += 256)
        histG[(size_t)b * nch + k] = h[b];
}

// Pass C: scatter packed (src | dstlow<<24) into per-(bucket,chunk) regions.
__global__ __launch_bounds__(256) void bucket_scatter(
    const int* __restrict__ ei, int E, int nbuc, int nch,
    const int* __restrict__ offs, unsigned int* __restrict__ ebuf) {
    __shared__ int cur[NBUC_MAX];
    const int k = blockIdx.x;
    for (int b = threadIdx.x; b < nbuc; b += 256)
        cur[b] = offs[(size_t)b * nch + k];
    __syncthreads();
    const int base = k * EPB, end = min(E, base + EPB);
    for (int i = base + threadIdx.x; i < end; i += 256) {
        int s = ei[i];
        int d = ei[(size_t)E + i];
        int pos = atomicAdd(&cur[d >> BSHIFT], 1);
        ebuf[pos] = (unsigned)s | ((unsigned)(d & 255) << 24);
    }
}

// Pass D: one block per bucket -> exact CSR slice (src-sorted rows) +
// deg/row_start/dinv + per-src-chunk row starts rsC[c][v].
__global__ __launch_bounds__(256) void bucket_build(
    const unsigned int* __restrict__ ebuf, const int* __restrict__ offs,
    int E, int nbuc, int nch, int n, int NC,
    int* __restrict__ col, int* __restrict__ deg,
    int* __restrict__ row_start, float* __restrict__ dinv,
    int* __restrict__ rsC) {
    const int b = blockIdx.x;
    const int tid = threadIdx.x;
    const int estart = offs[(size_t)b * nch];
    const int eend = (b + 1 < nbuc) ? offs[(size_t)(b + 1) * nch] : E;
    const int cnt = eend - estart;

    __shared__ int degl[256];
    __shared__ int curl[256];
    __shared__ int wsum[4];
    __shared__ int colstage[BCAP];

    degl[tid] = 0;
    __syncthreads();
    for (int i = tid; i < cnt; i += 256)
        atomicAdd(&degl[ebuf[estart + i] >> 24], 1);
    __syncthreads();
    int myDeg = degl[tid];
    int val = myDeg;
    int lane = tid & 63, w = tid >> 6;
#pragma unroll
    for (int off = 1; off < 64; off <<= 1) {
        int t = __shfl_up(val, off, 64);
        if (lane >= off) val += t;
    }
    if (lane == 63) wsum[w] = val;
    __syncthreads();
#pragma unroll
    for (int i = 0; i < 4; ++i)
        if (i < w) val += wsum[i];
    int excl = val - myDeg;
    curl[tid] = excl;
    int v = (b << BSHIFT) + tid;
    if (v < n) {
        deg[v] = myDeg;
        row_start[v] = estart + excl;
        dinv[v] = rsqrtf((float)(myDeg + 1));   // +1 self loop
    }
    __syncthreads();
    if (cnt <= BCAP) {
        for (int i = tid; i < cnt; i += 256) {
            unsigned int e = ebuf[estart + i];
            int pos = atomicAdd(&curl[e >> 24], 1);
            colstage[pos] = (int)(e & 0xFFFFFFu);
        }
        __syncthreads();
        // sort own row segment [excl, excl+myDeg) by src id (insertion sort;
        // segments are disjoint per thread -> no races)
        for (int a = excl + 1; a < excl + myDeg; ++a) {
            int key = colstage[a];
            int p = a - 1;
            while (p >= excl && colstage[p] > key) {
                colstage[p + 1] = colstage[p];
                --p;
            }
            colstage[p + 1] = key;
        }
        // per-chunk starts from the sorted row
        if (v < n) {
            int idx = 0;
            for (int c = 0; c < NC; ++c) {
                rsC[(size_t)c * n + v] = estart + excl + idx;
                while (idx < myDeg && (colstage[excl + idx] >> CSH) == c) ++idx;
            }
        }
        __syncthreads();   // all rows sorted before block-wide copy-out
        for (int i = tid; i < cnt; i += 256)
            col[estart + i] = colstage[i];
    } else {  // safety fallback: unsorted; pass 0 covers whole row (correct)
        for (int i = tid; i < cnt; i += 256) {
            unsigned int e = ebuf[estart + i];
            int pos = atomicAdd(&curl[e >> 24], 1);
            col[estart + pos] = (int)(e & 0xFFFFFFu);
        }
        if (v < n) {
            rsC[v] = estart + excl;                       // chunk 0: all
            for (int c = 1; c < NC; ++c)
                rsC[(size_t)c * n + v] = estart + excl + myDeg;  // empty
        }
    }
}

// --- bf16 helpers ---
__device__ inline unsigned short f32_to_bf16_rn(float f) {
    unsigned int u = __float_as_uint(f);
    unsigned int r = (u + 0x7FFFu + ((u >> 16) & 1u)) >> 16;
    return (unsigned short)r;
}
__device__ inline float bf16_to_f32(unsigned short h) {
    return __uint_as_float(((unsigned int)h) << 16);
}

// Pre-pack W (FIN x FOUT, f32) into fragment-ordered hi/lo bf16.
template <int FIN, int FOUT>
__global__ __launch_bounds__(256) void pack_w(const float* __restrict__ W,
                                              unsigned short* __restrict__ Wpk) {
    constexpr int KC = FIN / 32, CF = FOUT / 16;
    constexpr int TOT = KC * CF * 64 * 8;
    int idx = blockIdx.x * 256 + threadIdx.x;
    if (idx >= TOT) return;
    int j = idx & 7;
    int lane = (idx >> 3) & 63;
    int cf = (idx >> 9) % CF;
    int kc = (idx >> 9) / CF;
    int k = kc * 32 + ((lane >> 4) * 8) + j;
    int c = cf * 16 + (lane & 15);
    float w = W[(size_t)k * FOUT + c];
    unsigned short h = f32_to_bf16_rn(w);
    unsigned short l = f32_to_bf16_rn(w - bf16_to_f32(h));
    size_t base = ((size_t)((kc * CF + cf) * 64 + lane)) * 16;
    Wpk[base + j] = h;
    Wpk[base + 8 + j] = l;
}

// MFMA GEMM: Hs = fp16( (X @ W) * dinv[row] ), bf16 3-term split.
template <int FIN, int FOUT>
__global__ __launch_bounds__(256) void gemm_mfma(
    const float* __restrict__ X, const unsigned short* __restrict__ Wpk,
    const float* __restrict__ dinv, __half* __restrict__ Hs, int n) {
    constexpr int KC = FIN / 32, CF = FOUT / 16;
    constexpr int BM = 4 * 16;        // 64 rows per block
    const int w = threadIdx.x >> 6, lane = threadIdx.x & 63;
    const int g = lane >> 4, rr = lane & 15;
    const int node0 = blockIdx.x * BM + w * 16;
    const int ko = g * 8;

    f32x4 acc[CF];
#pragma unroll
    for (int cf = 0; cf < CF; ++cf)
        acc[cf] = (f32x4){0.f, 0.f, 0.f, 0.f};

    union U16 { uint4 u; short8 s; };

#pragma unroll 2
    for (int kc = 0; kc < KC; ++kc) {
        short8 ahi, alo;
        {
            int r = node0 + rr;
            float xv[8] = {0.f, 0.f, 0.f, 0.f, 0.f, 0.f, 0.f, 0.f};
            if (r < n) {
                const float* xp = X + (size_t)r * FIN + kc * 32 + ko;
                float4 a0 = *(const float4*)xp;
                float4 a1 = *(const float4*)(xp + 4);
                xv[0] = a0.x; xv[1] = a0.y; xv[2] = a0.z; xv[3] = a0.w;
                xv[4] = a1.x; xv[5] = a1.y; xv[6] = a1.z; xv[7] = a1.w;
            }
#pragma unroll
            for (int j = 0; j < 8; ++j) {
                unsigned int u = __float_as_uint(xv[j]);
                ahi[j] = (short)(unsigned short)(u >> 16);       // trunc hi
                float hf = __uint_as_float(u & 0xFFFF0000u);
                alo[j] = (short)f32_to_bf16_rn(xv[j] - hf);      // exact-ish lo
            }
        }
#pragma unroll
        for (int cf = 0; cf < CF; ++cf) {
            const uint4* bp = (const uint4*)(Wpk +
                ((size_t)((kc * CF + cf) * 64 + lane)) * 16);
            U16 bh, bl;
            bh.u = bp[0];
            bl.u = bp[1];
            acc[cf] = __builtin_amdgcn_mfma_f32_16x16x32_bf16(
                ahi, bh.s, acc[cf], 0, 0, 0);
            acc[cf] = __builtin_amdgcn_mfma_f32_16x16x32_bf16(
                alo, bh.s, acc[cf], 0, 0, 0);
            acc[cf] = __builtin_amdgcn_mfma_f32_16x16x32_bf16(
                ahi, bl.s, acc[cf], 0, 0, 0);
        }
    }

    // D layout (HW-verified): col = lane&15, row = (lane>>4)*4 + reg.
#pragma unroll
    for (int i = 0; i < 4; ++i) {
        int r = node0 + g * 4 + i;
        if (r >= n) continue;
        float di = dinv[r];
        __half* hp = Hs + (size_t)r * FOUT + rr;
#pragma unroll
        for (int cf = 0; cf < CF; ++cf)
            hp[cf * 16] = __float2half_rn(acc[cf][i] * di);
    }
}

// Register-tiled f32 GEMM (layer 3: 64 -> 16). Row-major input.
template <int FIN, int FOUT, int TM>
__global__ __launch_bounds__(256) void gemm_tile_h(
    const float* __restrict__ X, const float* __restrict__ W,
    const float* __restrict__ dinv, __half* __restrict__ Hs, int n) {
    constexpr int CT = FOUT / 4;
    constexpr int RG = 256 / CT;
    static_assert(TM == RG * 4, "tile mismatch");
    constexpr int LROW = FIN + 4;
    __shared__ float xs[TM][LROW];

    const int node0 = blockIdx.x * TM;
    const int tid = threadIdx.x;

    constexpr int C4 = FIN / 4;
    for (int i = tid; i < TM * C4; i += 256) {
        int r = i / C4, c = (i % C4) * 4;
        float4 v = make_float4(0.f, 0.f, 0.f, 0.f);
        if (node0 + r < n) v = *(const float4*)(X + (size_t)(node0 + r) * FIN + c);
        *(float4*)&xs[r][c] = v;
    }
    __syncthreads();

    const int col = (tid % CT) * 4;
    const int r0 = (tid / CT) * 4;

    float acc[4][4];
#pragma unroll
    for (int i = 0; i < 4; ++i)
#pragma unroll
        for (int j = 0; j < 4; ++j) acc[i][j] = 0.f;

#pragma unroll 2
    for (int k = 0; k < FIN; k += 4) {
        float4 w0 = *(const float4*)(W + (size_t)(k + 0) * FOUT + col);
        float4 w1 = *(const float4*)(W + (size_t)(k + 1) * FOUT + col);
        float4 w2 = *(const float4*)(W + (size_t)(k + 2) * FOUT + col);
        float4 w3 = *(const float4*)(W + (size_t)(k + 3) * FOUT + col);
        float4 av[4];
        av[0] = *(const float4*)&xs[r0 + 0][k];
        av[1] = *(const float4*)&xs[r0 + 1][k];
        av[2] = *(const float4*)&xs[r0 + 2][k];
        av[3] = *(const float4*)&xs[r0 + 3][k];
#pragma unroll
        for (int rr = 0; rr < 4; ++rr) {
            acc[rr][0] = fmaf(av[rr].x, w0.x, acc[rr][0]);
            acc[rr][1] = fmaf(av[rr].x, w0.y, acc[rr][1]);
            acc[rr][2] = fmaf(av[rr].x, w0.z, acc[rr][2]);
            acc[rr][3] = fmaf(av[rr].x, w0.w, acc[rr][3]);
            acc[rr][0] = fmaf(av[rr].y, w1.x, acc[rr][0]);
            acc[rr][1] = fmaf(av[rr].y, w1.y, acc[rr][1]);
            acc[rr][2] = fmaf(av[rr].y, w1.z, acc[rr][2]);
            acc[rr][3] = fmaf(av[rr].y, w1.w, acc[rr][3]);
            acc[rr][0] = fmaf(av[rr].z, w2.x, acc[rr][0]);
            acc[rr][1] = fmaf(av[rr].z, w2.y, acc[rr][1]);
            acc[rr][2] = fmaf(av[rr].z, w2.z, acc[rr][2]);
            acc[rr][3] = fmaf(av[rr].z, w2.w, acc[rr][3]);
            acc[rr][0] = fmaf(av[rr].w, w3.x, acc[rr][0]);
            acc[rr][1] = fmaf(av[rr].w, w3.y, acc[rr][1]);
            acc[rr][2] = fmaf(av[rr].w, w3.z, acc[rr][2]);
            acc[rr][3] = fmaf(av[rr].w, w3.w, acc[rr][3]);
        }
    }

#pragma unroll
    for (int rr = 0; rr < 4; ++rr) {
        int node = node0 + r0 + rr;
        if (node < n) {
            float di = dinv[node];
            __half h0 = __float2half_rn(acc[rr][0] * di);
            __half h1 = __float2half_rn(acc[rr][1] * di);
            __half h2 = __float2half_rn(acc[rr][2] * di);
            __half h3 = __float2half_rn(acc[rr][3] * di);
            unsigned short u0 = *(unsigned short*)&h0, u1 = *(unsigned short*)&h1;
            unsigned short u2 = *(unsigned short*)&h2, u3 = *(unsigned short*)&h3;
            uint2 pk;
            pk.x = (unsigned)u0 | ((unsigned)u1 << 16);
            pk.y = (unsigned)u2 | ((unsigned)u3 << 16);
            *(uint2*)(Hs + (size_t)node * FOUT + col) = pk;
        }
    }
}

__device__ inline void add8h(float* acc, uint4 p) {
    unsigned int w[4] = {p.x, p.y, p.z, p.w};
#pragma unroll
    for (int t = 0; t < 4; ++t) {
        __half2 h = *(const __half2*)&w[t];
        float2 f = __half22float2(h);
        acc[2 * t] += f.x;
        acc[2 * t + 1] += f.y;
    }
}

// Src-chunked pull: persistent grid, NPT nodes per thread with register
// accumulators across the chunk-pass loop. All resident blocks sweep chunk c
// together -> per-pass gather footprint (n>>CSH)*F*2 B is L2-resident.
// Rows are src-sorted; chunk-c subrange = [rsC[c][v], rsC[c+1][v]).
template <int F, int NPT>
__global__ __launch_bounds__(256) void pull_chunk(
    const int* __restrict__ rsC, const int* __restrict__ row_start,
    const int* __restrict__ deg, const int* __restrict__ col,
    const __half* __restrict__ Hs, const float* __restrict__ dinv,
    const float* __restrict__ B, float* __restrict__ OUT, int n, int NC) {
    constexpr int TPE = F / 8;
    const int T = blockIdx.x * 256 + threadIdx.x;
    const int STEP = (int)gridDim.x * 256;

    float acc[NPT][8];
#pragma unroll
    for (int i = 0; i < NPT; ++i)
#pragma unroll
        for (int k = 0; k < 8; ++k) acc[i][k] = 0.f;

    // self terms
#pragma unroll
    for (int i = 0; i < NPT; ++i) {
        int gid = T + i * STEP;
        int node = gid / TPE;
        if (node < n) {
            int lane = gid & (TPE - 1);
            add8h(acc[i], *(const uint4*)(Hs + (size_t)node * F + lane * 8));
        }
    }

    for (int c = 0; c < NC; ++c) {
#pragma unroll
        for (int i = 0; i < NPT; ++i) {
            int gid = T + i * STEP;
            int node = gid / TPE;
            if (node >= n) continue;
            int lane = gid & (TPE - 1);
            const size_t lo = (size_t)lane * 8;
            int j = rsC[(size_t)c * n + node];
            int end = (c + 1 < NC) ? rsC[(size_t)(c + 1) * n + node]
                                   : row_start[node] + deg[node];
            for (; j + 4 <= end; j += 4) {
                int s0 = col[j + 0], s1 = col[j + 1];
                int s2 = col[j + 2], s3 = col[j + 3];
                uint4 p0 = *(const uint4*)(Hs + (size_t)s0 * F + lo);
                uint4 p1 = *(const uint4*)(Hs + (size_t)s1 * F + lo);
                uint4 p2 = *(const uint4*)(Hs + (size_t)s2 * F + lo);
                uint4 p3 = *(const uint4*)(Hs + (size_t)s3 * F + lo);
                add8h(acc[i], p0); add8h(acc[i], p1);
                add8h(acc[i], p2); add8h(acc[i], p3);
            }
            for (; j < end; ++j) {
                int s = col[j];
                add8h(acc[i], *(const uint4*)(Hs + (size_t)s * F + lo));
            }
        }
    }

#pragma unroll
    for (int i = 0; i < NPT; ++i) {
        int gid = T + i * STEP;
        int node = gid / TPE;
        if (node >= n) continue;
        int lane = gid & (TPE - 1);
        const size_t lo = (size_t)lane * 8;
        float di = dinv[node];
        float4 b0 = *(const float4*)(B + lo);
        float4 b1 = *(const float4*)(B + lo + 4);
        float4 r0, r1;
        r0.x = tanhf(fmaf(acc[i][0], di, b0.x));
        r0.y = tanhf(fmaf(acc[i][1], di, b0.y));
        r0.z = tanhf(fmaf(acc[i][2], di, b0.z));
        r0.w = tanhf(fmaf(acc[i][3], di, b0.w));
        r1.x = tanhf(fmaf(acc[i][4], di, b1.x));
        r1.y = tanhf(fmaf(acc[i][5], di, b1.y));
        r1.z = tanhf(fmaf(acc[i][6], di, b1.z));
        r1.w = tanhf(fmaf(acc[i][7], di, b1.w));
        float* op = OUT + (size_t)node * F + lo;
        *(float4*)(op) = r0;
        *(float4*)(op + 4) = r1;
    }
}

// Layer-3 pull (16 feats, table 3.2 MB, already L2-fit) + fused classifier.
__global__ __launch_bounds__(256) void pull_cls(
    const int* __restrict__ row_start, const int* __restrict__ deg,
    const int* __restrict__ col, const __half* __restrict__ Hs,
    const float* __restrict__ dinv, const float* __restrict__ B,
    const float* __restrict__ Wc, const float* __restrict__ bc,
    float* __restrict__ OUTH, float* __restrict__ OUTC, int n) {
    int gid = blockIdx.x * 256 + threadIdx.x;
    int node = gid >> 1;
    if (node >= n) return;
    const int half = gid & 1;
    const size_t lo = (size_t)half * 8;
    const int beg = row_start[node];
    const int cnt = deg[node];

    float acc[8] = {0.f, 0.f, 0.f, 0.f, 0.f, 0.f, 0.f, 0.f};
    add8h(acc, *(const uint4*)(Hs + (size_t)node * 16 + lo));  // self term

    int j = 0;
    for (; j + 8 <= cnt; j += 8) {
        int s0 = col[beg + j + 0], s1 = col[beg + j + 1];
        int s2 = col[beg + j + 2], s3 = col[beg + j + 3];
        int s4 = col[beg + j + 4], s5 = col[beg + j + 5];
        int s6 = col[beg + j + 6], s7 = col[beg + j + 7];
        uint4 p0 = *(const uint4*)(Hs + (size_t)s0 * 16 + lo);
        uint4 p1 = *(const uint4*)(Hs + (size_t)s1 * 16 + lo);
        uint4 p2 = *(const uint4*)(Hs + (size_t)s2 * 16 + lo);
        uint4 p3 = *(const uint4*)(Hs + (size_t)s3 * 16 + lo);
        uint4 p4 = *(const uint4*)(Hs + (size_t)s4 * 16 + lo);
        uint4 p5 = *(const uint4*)(Hs + (size_t)s5 * 16 + lo);
        uint4 p6 = *(const uint4*)(Hs + (size_t)s6 * 16 + lo);
        uint4 p7 = *(const uint4*)(Hs + (size_t)s7 * 16 + lo);
        add8h(acc, p0); add8h(acc, p1); add8h(acc, p2); add8h(acc, p3);
        add8h(acc, p4); add8h(acc, p5); add8h(acc, p6); add8h(acc, p7);
    }
    for (; j < cnt; ++j) {
        int s = col[beg + j];
        add8h(acc, *(const uint4*)(Hs + (size_t)s * 16 + lo));
    }

    float di = dinv[node];
    float r[8];
#pragma unroll
    for (int k = 0; k < 8; ++k)
        r[k] = tanhf(fmaf(acc[k], di, B[lo + k]));

    float* op = OUTH + (size_t)node * 16 + lo;
    *(float4*)(op)     = make_float4(r[0], r[1], r[2], r[3]);
    *(float4*)(op + 4) = make_float4(r[4], r[5], r[6], r[7]);

    float o0 = 0.f, o1 = 0.f;
#pragma unroll
    for (int k = 0; k < 8; ++k) {
        o0 = fmaf(r[k], Wc[(lo + k) * 2 + 0], o0);
        o1 = fmaf(r[k], Wc[(lo + k) * 2 + 1], o1);
    }
    o0 += __shfl_xor(o0, 1);
    o1 += __shfl_xor(o1, 1);
    if (half == 0) {
        OUTC[(size_t)node * 2 + 0] = o0 + bc[0];
        OUTC[(size_t)node * 2 + 1] = o1 + bc[1];
    }
}

extern "C" void kernel_launch(void* const* d_in, const int* in_sizes, int n_in,
                              void* d_out, int out_size, void* d_ws, size_t ws_size,
                              hipStream_t stream) {
    const float* x  = (const float*)d_in[0];
    const int* ei   = (const int*)d_in[1];   // int32 (harness converts)
    const float* W1 = (const float*)d_in[2];
    const float* b1 = (const float*)d_in[3];
    const float* W2 = (const float*)d_in[4];
    const float* b2 = (const float*)d_in[5];
    const float* W3 = (const float*)d_in[6];
    const float* b3 = (const float*)d_in[7];
    const float* Wc = (const float*)d_in[8];
    const float* bc = (const float*)d_in[9];

    const int n = in_sizes[0] / 256;
    const int E = in_sizes[1] / 2;
    const int nbuc = (n + 255) >> BSHIFT;          // 391
    const int nch  = (E + EPB - 1) / EPB;          // 196
    const int NH   = nbuc * nch;                   // 76,636
    const int nb2  = (NH + 255) / 256;             // 300 <= 512
    const int NC   = (n + (1 << CSH) - 1) >> CSH;  // 13 src chunks

    float* outp = (float*)d_out;             // [n,2]
    float* outh = outp + (size_t)n * 2;      // [n,16]

    int*    deg       = (int*)d_ws;
    float*  dinv      = (float*)d_ws + (size_t)n;
    int*    row_start = (int*)d_ws + 2 * (size_t)n;
    int*    histG     = (int*)d_ws + 3 * (size_t)n;
    int*    incl      = histG + NH;
    int*    bsum      = incl + NH;
    int*    offs      = bsum + 512;
    int*    col       = offs + NH;
    __half* HsH       = (__half*)(col + E);  // row-major [n][FOUT]
    float*  xbuf      = (float*)(HsH + (size_t)n * 128);  // row-major f32
    int*    rsC       = (int*)(xbuf + (size_t)n * 128);   // [NC][n] chunk starts
    unsigned int* ebuf = (unsigned int*)xbuf;  // alias: dead before pull writes

    // Packed-W buffers alias histG (NH*4 = 306 KB; dead after finalize_scan).
    unsigned short* Wpk1 = (unsigned short*)histG;
    unsigned short* Wpk2 = Wpk1 + (size_t)256 * 128 * 2;

    // --- atomic-free CSR build (shared by all 3 layers) ---
    hist_bucket<<<nch, 256, 0, stream>>>(ei, E, nbuc, nch, histG);
    scan_block<<<nb2, 256, 0, stream>>>(histG, NH, incl, bsum);
    scan_sums<<<1, 512, 0, stream>>>(bsum, nb2);
    finalize_scan<<<nb2, 256, 0, stream>>>(incl, bsum, histG, NH, offs);
    bucket_scatter<<<nch, 256, 0, stream>>>(ei, E, nbuc, nch, offs, ebuf);
    bucket_build<<<nbuc, 256, 0, stream>>>(ebuf, offs, E, nbuc, nch, n, NC,
                                           col, deg, row_start, dinv, rsC);

    // --- pack W1/W2 into MFMA fragment order (histG dead by now) ---
    pack_w<256, 128><<<(256 / 32 * 128 / 16 * 512 + 255) / 256, 256, 0, stream>>>(W1, Wpk1);
    pack_w<128, 64><<<(128 / 32 * 64 / 16 * 512 + 255) / 256, 256, 0, stream>>>(W2, Wpk2);

    // persistent pull grids: 128 nodes/block for both layers -> 782 blocks
    const int G1 = (n + 127) / 128;   // F=128, NPT=8
    const int G2 = (n + 127) / 128;   // F=64,  NPT=4

    // --- layer 1: 256 -> 128 (MFMA) ---
    gemm_mfma<256, 128><<<(n + 63) / 64, 256, 0, stream>>>(x, Wpk1, dinv, HsH, n);
    pull_chunk<128, 8><<<G1, 256, 0, stream>>>(rsC, row_start, deg, col, HsH,
                                               dinv, b1, xbuf, n, NC);

    // --- layer 2: 128 -> 64 (MFMA) ---
    gemm_mfma<128, 64><<<(n + 63) / 64, 256, 0, stream>>>(xbuf, Wpk2, dinv, HsH, n);
    pull_chunk<64, 4><<<G2, 256, 0, stream>>>(rsC, row_start, deg, col, HsH,
                                              dinv, b2, xbuf, n, NC);

    // --- layer 3: 64 -> 16 (f32 path) + fused classifier pull ---
    gemm_tile_h<64, 16, 256><<<(n + 255) / 256, 256, 0, stream>>>(xbuf, W3, dinv, HsH, n);
    pull_cls<<<(2 * n + 255) / 256, 256, 0, stream>>>(row_start, deg, col, HsH,
                                                      dinv, b3, Wc, bc, outh, outp, n);
}

// Round 7
// 611.469 us; speedup vs baseline: 1.8184x; 1.8184x over previous
//
#include <hip/hip_runtime.h>
#include <hip/hip_fp16.h>
#include <cstdint>
#include <cstddef>

// ---------------------------------------------------------------------------
// GCNClassifier: 3x (GCNConv + tanh) + linear head, N=100k nodes, E=3.2M edges
// Round 16 = round 15 + swizzle-read fix.
// Round-15 bug: lo-half B chunk stored at swz(a0+16) but read at swz(a0)+16.
// These differ when (a0>>7)&1 == 1; worst case reads past the slice/LDS end
// (garbage -> NaN). Fix: read lo at swz(a0+16). Both addresses stay within
// their 64-byte block by construction -> no OOB possible.
// Design (unchanged): B staged in LDS per kc-slice, double-buffered; swizzle
// baked into Wpk by pack_w so staging is a linear copy; BM=128/RF=2, one
// barrier per kc. Attacks round-2 profile (gemm1 68us @ MfmaUtil 10.6%).
// CSR build, pulls, pull_cls, layer-3 gemm: round-12 versions unchanged.
// ---------------------------------------------------------------------------

#define EPB 16384        // edges per hist/scatter chunk
#define BSHIFT 8         // bucket = dst >> 8 (256 dst nodes per bucket)
#define NBUC_MAX 512     // 100000>>8 = 390 max bucket id
#define BCAP 12800       // bucket_build LDS edge capacity (avg 8192, 50+ sigma)

typedef __attribute__((ext_vector_type(8))) short short8;
typedef __attribute__((ext_vector_type(4))) float f32x4;

// --- generic two-level exclusive scan ---
__global__ __launch_bounds__(256) void scan_block(const int* __restrict__ src, int n,
                                                  int* __restrict__ incl,
                                                  int* __restrict__ bsum) {
    int tid = threadIdx.x;
    int v = blockIdx.x * 256 + tid;
    int val = (v < n) ? src[v] : 0;
    int lane = tid & 63, w = tid >> 6;
#pragma unroll
    for (int off = 1; off < 64; off <<= 1) {
        int t = __shfl_up(val, off, 64);
        if (lane >= off) val += t;
    }
    __shared__ int wsum[4];
    if (lane == 63) wsum[w] = val;
    __syncthreads();
#pragma unroll
    for (int i = 0; i < 4; ++i)
        if (i < w) val += wsum[i];
    if (v < n) incl[v] = val;
    if (tid == 255) bsum[blockIdx.x] = val;
}

__global__ __launch_bounds__(512) void scan_sums(int* __restrict__ bsum, int nb) {
    int tid = threadIdx.x;              // nb <= 512
    int val = (tid < nb) ? bsum[tid] : 0;
    int lane = tid & 63, w = tid >> 6;
#pragma unroll
    for (int off = 1; off < 64; off <<= 1) {
        int t = __shfl_up(val, off, 64);
        if (lane >= off) val += t;
    }
    __shared__ int wsum[8];
    if (lane == 63) wsum[w] = val;
    __syncthreads();
#pragma unroll
    for (int i = 0; i < 8; ++i)
        if (i < w) val += wsum[i];
    if (tid < nb) bsum[tid] = val;
}

__global__ __launch_bounds__(256) void finalize_scan(
    const int* __restrict__ incl, const int* __restrict__ bsum,
    const int* __restrict__ src, int n, int* __restrict__ excl) {
    int v = blockIdx.x * 256 + threadIdx.x;
    if (v >= n) return;
    int boff = (blockIdx.x == 0) ? 0 : bsum[blockIdx.x - 1];
    excl[v] = boff + incl[v] - src[v];
}

// Pass A: per-chunk histogram over dst buckets (LDS atomics only).
__global__ __launch_bounds__(256) void hist_bucket(
    const int* __restrict__ ei, int E, int nbuc, int nch,
    int* __restrict__ histG) {
    __shared__ int h[NBUC_MAX];
    const int k = blockIdx.x;
    for (int b = threadIdx.x; b < NBUC_MAX; b += 256) h[b] = 0;
    __syncthreads();
    const int base = k * EPB, end = min(E, base + EPB);
    for (int i = base + threadIdx.x; i < end; i += 256)
        atomicAdd(&h[ei[(size_t)E + i] >> BSHIFT], 1);
    __syncthreads();
    for (int b = threadIdx.x; b < nbuc; b += 256)
        histG[(size_t)b * nch + k] = h[b];
}

// Pass C: scatter packed (src | dstlow<<24) into per-(bucket,chunk) regions.
// src < 2^24 (n = 100k), dstlow = dst & 255 -> 4 B payload instead of 8 B.
__global__ __launch_bounds__(256) void bucket_scatter(
    const int* __restrict__ ei, int E, int nbuc, int nch,
    const int* __restrict__ offs, unsigned int* __restrict__ ebuf) {
    __shared__ int cur[NBUC_MAX];
    const int k = blockIdx.x;
    for (int b = threadIdx.x; b < nbuc; b += 256)
        cur[b] = offs[(size_t)b * nch + k];
    __syncthreads();
    const int base = k * EPB, end = min(E, base + EPB);
    for (int i = base + threadIdx.x; i < end; i += 256) {
        int s = ei[i];
        int d = ei[(size_t)E + i];
        int pos = atomicAdd(&cur[d >> BSHIFT], 1);
        ebuf[pos] = (unsigned)s | ((unsigned)(d & 255) << 24);
    }
}

// Pass D: one block per bucket -> exact CSR slice + deg/row_start/dinv.
__global__ __launch_bounds__(256) void bucket_build(
    const unsigned int* __restrict__ ebuf, const int* __restrict__ offs,
    int E, int nbuc, int nch, int n,
    int* __restrict__ col, int* __restrict__ deg,
    int* __restrict__ row_start, float* __restrict__ dinv) {
    const int b = blockIdx.x;
    const int tid = threadIdx.x;
    const int estart = offs[(size_t)b * nch];
    const int eend = (b + 1 < nbuc) ? offs[(size_t)(b + 1) * nch] : E;
    const int cnt = eend - estart;

    __shared__ int degl[256];
    __shared__ int curl[256];
    __shared__ int wsum[4];
    __shared__ int colstage[BCAP];

    degl[tid] = 0;
    __syncthreads();
    for (int i = tid; i < cnt; i += 256)
        atomicAdd(&degl[ebuf[estart + i] >> 24], 1);
    __syncthreads();
    int myDeg = degl[tid];
    int val = myDeg;
    int lane = tid & 63, w = tid >> 6;
#pragma unroll
    for (int off = 1; off < 64; off <<= 1) {
        int t = __shfl_up(val, off, 64);
        if (lane >= off) val += t;
    }
    if (lane == 63) wsum[w] = val;
    __syncthreads();
#pragma unroll
    for (int i = 0; i < 4; ++i)
        if (i < w) val += wsum[i];
    int excl = val - myDeg;
    curl[tid] = excl;
    int v = (b << BSHIFT) + tid;
    if (v < n) {
        deg[v] = myDeg;
        row_start[v] = estart + excl;
        dinv[v] = rsqrtf((float)(myDeg + 1));   // +1 self loop
    }
    __syncthreads();
    if (cnt <= BCAP) {
        for (int i = tid; i < cnt; i += 256) {
            unsigned int e = ebuf[estart + i];
            int pos = atomicAdd(&curl[e >> 24], 1);
            colstage[pos] = (int)(e & 0xFFFFFFu);
        }
        __syncthreads();
        for (int i = tid; i < cnt; i += 256)
            col[estart + i] = colstage[i];
    } else {  // safety fallback
        for (int i = tid; i < cnt; i += 256) {
            unsigned int e = ebuf[estart + i];
            int pos = atomicAdd(&curl[e >> 24], 1);
            col[estart + pos] = (int)(e & 0xFFFFFFu);
        }
    }
}

// --- bf16 helpers ---
__device__ inline unsigned short f32_to_bf16_rn(float f) {
    unsigned int u = __float_as_uint(f);
    unsigned int r = (u + 0x7FFFu + ((u >> 16) & 1u)) >> 16;
    return (unsigned short)r;
}
__device__ inline float bf16_to_f32(unsigned short h) {
    return __uint_as_float(((unsigned int)h) << 16);
}

// LDS bank swizzle on slice-local byte address (involution, XORs bits 4-5
// with bits 7-8). Stays within the 64-byte block of its argument.
__device__ __host__ inline int swz(int a) {
    return a ^ (((a >> 7) & 3) << 4);
}

// Pre-pack W (FIN x FOUT, f32) into kc-sliced, SWIZZLED fragment order.
// Natural slice-local layout: short s at byte a = (cf*64+lane)*32 + half*16
// + j*2 where frag value j of lane l covers W[kc*32+(l>>4)*8+j][cf*16+(l&15)],
// half 0 = hi bf16, half 1 = lo bf16. Each 16-byte chunk is stored at
// swz(chunk_base); within a chunk bytes stay contiguous (XOR constant).
template <int FIN, int FOUT>
__global__ __launch_bounds__(256) void pack_w(const float* __restrict__ W,
                                              unsigned short* __restrict__ Wpk) {
    constexpr int KC = FIN / 32, CF = FOUT / 16;
    constexpr int SLICE = CF * 64 * 16;   // shorts per kc-slice
    constexpr int TOT = KC * CF * 64 * 8;
    int idx = blockIdx.x * 256 + threadIdx.x;
    if (idx >= TOT) return;
    int j = idx & 7;
    int lane = (idx >> 3) & 63;
    int cf = (idx >> 9) % CF;
    int kc = (idx >> 9) / CF;
    int k = kc * 32 + ((lane >> 4) * 8) + j;
    int c = cf * 16 + (lane & 15);
    float w = W[(size_t)k * FOUT + c];
    unsigned short h = f32_to_bf16_rn(w);
    unsigned short l = f32_to_bf16_rn(w - bf16_to_f32(h));
    int ah = (cf * 64 + lane) * 32 + j * 2;        // hi half byte addr
    int al = ah + 16;                              // lo half byte addr
    Wpk[(size_t)kc * SLICE + (swz(ah) >> 1)] = h;
    Wpk[(size_t)kc * SLICE + (swz(al) >> 1)] = l;
}

// MFMA GEMM: Hs = fp16( (X @ W) * dinv[row] ), bf16 3-term split:
// acc += Xhi*Whi + Xlo*Whi + Xhi*Wlo.
// B staged in LDS per kc-slice, double-buffered; linear copy (swizzle baked
// into Wpk), ds_read_b128 with swz() addressing. BM=128 (RF=2), 1 barrier/kc.
template <int FIN, int FOUT>
__global__ __launch_bounds__(256) void gemm_mfma(
    const float* __restrict__ X, const unsigned short* __restrict__ Wpk,
    const float* __restrict__ dinv, __half* __restrict__ Hs, int n) {
    constexpr int KC = FIN / 32, CF = FOUT / 16, RF = 2;
    constexpr int BM = 4 * RF * 16;       // 128 rows per block
    constexpr int SLICE = CF * 64 * 16;   // shorts per kc-slice
    constexpr int NV = SLICE / 8;         // uint4 per slice
    __shared__ __align__(16) unsigned short bsh[2 * SLICE];

    const int tid = threadIdx.x;
    const int w = tid >> 6, lane = tid & 63;
    const int g = lane >> 4, rr = lane & 15;
    const int node0 = blockIdx.x * BM + w * (RF * 16);
    const int ko = g * 8;

    f32x4 acc[RF][CF];
#pragma unroll
    for (int rf = 0; rf < RF; ++rf)
#pragma unroll
        for (int cf = 0; cf < CF; ++cf)
            acc[rf][cf] = (f32x4){0.f, 0.f, 0.f, 0.f};

    union U16 { uint4 u; short8 s; };

    // stage slice 0
    {
        const uint4* src = (const uint4*)Wpk;
        uint4* dst = (uint4*)bsh;
#pragma unroll
        for (int i = 0; i < NV / 256; ++i) dst[i * 256 + tid] = src[i * 256 + tid];
    }
    __syncthreads();

#pragma unroll
    for (int kc = 0; kc < KC; ++kc) {
        // prefetch next slice into the other buffer (write-after-read safe:
        // that buffer's reads completed before the previous barrier)
        if (kc + 1 < KC) {
            const uint4* src = (const uint4*)(Wpk + (size_t)(kc + 1) * SLICE);
            uint4* dst = (uint4*)(bsh + ((kc + 1) & 1) * SLICE);
#pragma unroll
            for (int i = 0; i < NV / 256; ++i) dst[i * 256 + tid] = src[i * 256 + tid];
        }

        short8 ahi[RF], alo[RF];
#pragma unroll
        for (int rf = 0; rf < RF; ++rf) {
            int r = node0 + rf * 16 + rr;
            float xv[8] = {0.f, 0.f, 0.f, 0.f, 0.f, 0.f, 0.f, 0.f};
            if (r < n) {
                const float* xp = X + (size_t)r * FIN + kc * 32 + ko;
                float4 a0 = *(const float4*)xp;
                float4 a1 = *(const float4*)(xp + 4);
                xv[0] = a0.x; xv[1] = a0.y; xv[2] = a0.z; xv[3] = a0.w;
                xv[4] = a1.x; xv[5] = a1.y; xv[6] = a1.z; xv[7] = a1.w;
            }
#pragma unroll
            for (int j = 0; j < 8; ++j) {
                unsigned int u = __float_as_uint(xv[j]);
                ahi[rf][j] = (short)(unsigned short)(u >> 16);   // trunc hi
                float hf = __uint_as_float(u & 0xFFFF0000u);
                alo[rf][j] = (short)f32_to_bf16_rn(xv[j] - hf);  // exact-ish lo
            }
        }

        const char* bufp = (const char*)(bsh + (kc & 1) * SLICE);
#pragma unroll
        for (int cf = 0; cf < CF; ++cf) {
            int a0 = (cf * 64 + lane) * 32;
            int ash = swz(a0);        // hi chunk
            int asl = swz(a0 + 16);   // lo chunk (FIX: swizzle independently)
            U16 bh, bl;
            bh.u = *(const uint4*)(bufp + ash);
            bl.u = *(const uint4*)(bufp + asl);
#pragma unroll
            for (int rf = 0; rf < RF; ++rf) {
                acc[rf][cf] = __builtin_amdgcn_mfma_f32_16x16x32_bf16(
                    ahi[rf], bh.s, acc[rf][cf], 0, 0, 0);
                acc[rf][cf] = __builtin_amdgcn_mfma_f32_16x16x32_bf16(
                    alo[rf], bh.s, acc[rf][cf], 0, 0, 0);
                acc[rf][cf] = __builtin_amdgcn_mfma_f32_16x16x32_bf16(
                    ahi[rf], bl.s, acc[rf][cf], 0, 0, 0);
            }
        }
        __syncthreads();
    }

    // D layout (HW-verified): col = lane&15, row = (lane>>4)*4 + reg.
#pragma unroll
    for (int rf = 0; rf < RF; ++rf) {
#pragma unroll
        for (int i = 0; i < 4; ++i) {
            int r = node0 + rf * 16 + g * 4 + i;
            if (r >= n) continue;
            float di = dinv[r];
            __half* hp = Hs + (size_t)r * FOUT + rr;
#pragma unroll
            for (int cf = 0; cf < CF; ++cf)
                hp[cf * 16] = __float2half_rn(acc[rf][cf][i] * di);
        }
    }
}

// Register-tiled f32 GEMM (layer 3: 64 -> 16). Row-major input.
template <int FIN, int FOUT, int TM>
__global__ __launch_bounds__(256) void gemm_tile_h(
    const float* __restrict__ X, const float* __restrict__ W,
    const float* __restrict__ dinv, __half* __restrict__ Hs, int n) {
    constexpr int CT = FOUT / 4;
    constexpr int RG = 256 / CT;
    static_assert(TM == RG * 4, "tile mismatch");
    constexpr int LROW = FIN + 4;
    __shared__ float xs[TM][LROW];

    const int node0 = blockIdx.x * TM;
    const int tid = threadIdx.x;

    constexpr int C4 = FIN / 4;
    for (int i = tid; i < TM * C4; i += 256) {
        int r = i / C4, c = (i % C4) * 4;
        float4 v = make_float4(0.f, 0.f, 0.f, 0.f);
        if (node0 + r < n) v = *(const float4*)(X + (size_t)(node0 + r) * FIN + c);
        *(float4*)&xs[r][c] = v;
    }
    __syncthreads();

    const int col = (tid % CT) * 4;
    const int r0 = (tid / CT) * 4;

    float acc[4][4];
#pragma unroll
    for (int i = 0; i < 4; ++i)
#pragma unroll
        for (int j = 0; j < 4; ++j) acc[i][j] = 0.f;

#pragma unroll 2
    for (int k = 0; k < FIN; k += 4) {
        float4 w0 = *(const float4*)(W + (size_t)(k + 0) * FOUT + col);
        float4 w1 = *(const float4*)(W + (size_t)(k + 1) * FOUT + col);
        float4 w2 = *(const float4*)(W + (size_t)(k + 2) * FOUT + col);
        float4 w3 = *(const float4*)(W + (size_t)(k + 3) * FOUT + col);
        float4 av[4];
        av[0] = *(const float4*)&xs[r0 + 0][k];
        av[1] = *(const float4*)&xs[r0 + 1][k];
        av[2] = *(const float4*)&xs[r0 + 2][k];
        av[3] = *(const float4*)&xs[r0 + 3][k];
#pragma unroll
        for (int rr = 0; rr < 4; ++rr) {
            acc[rr][0] = fmaf(av[rr].x, w0.x, acc[rr][0]);
            acc[rr][1] = fmaf(av[rr].x, w0.y, acc[rr][1]);
            acc[rr][2] = fmaf(av[rr].x, w0.z, acc[rr][2]);
            acc[rr][3] = fmaf(av[rr].x, w0.w, acc[rr][3]);
            acc[rr][0] = fmaf(av[rr].y, w1.x, acc[rr][0]);
            acc[rr][1] = fmaf(av[rr].y, w1.y, acc[rr][1]);
            acc[rr][2] = fmaf(av[rr].y, w1.z, acc[rr][2]);
            acc[rr][3] = fmaf(av[rr].y, w1.w, acc[rr][3]);
            acc[rr][0] = fmaf(av[rr].z, w2.x, acc[rr][0]);
            acc[rr][1] = fmaf(av[rr].z, w2.y, acc[rr][1]);
            acc[rr][2] = fmaf(av[rr].z, w2.z, acc[rr][2]);
            acc[rr][3] = fmaf(av[rr].z, w2.w, acc[rr][3]);
            acc[rr][0] = fmaf(av[rr].w, w3.x, acc[rr][0]);
            acc[rr][1] = fmaf(av[rr].w, w3.y, acc[rr][1]);
            acc[rr][2] = fmaf(av[rr].w, w3.z, acc[rr][2]);
            acc[rr][3] = fmaf(av[rr].w, w3.w, acc[rr][3]);
        }
    }

#pragma unroll
    for (int rr = 0; rr < 4; ++rr) {
        int node = node0 + r0 + rr;
        if (node < n) {
            float di = dinv[node];
            __half h0 = __float2half_rn(acc[rr][0] * di);
            __half h1 = __float2half_rn(acc[rr][1] * di);
            __half h2 = __float2half_rn(acc[rr][2] * di);
            __half h3 = __float2half_rn(acc[rr][3] * di);
            unsigned short u0 = *(unsigned short*)&h0, u1 = *(unsigned short*)&h1;
            unsigned short u2 = *(unsigned short*)&h2, u3 = *(unsigned short*)&h3;
            uint2 pk;
            pk.x = (unsigned)u0 | ((unsigned)u1 << 16);
            pk.y = (unsigned)u2 | ((unsigned)u3 << 16);
            *(uint2*)(Hs + (size_t)node * FOUT + col) = pk;
        }
    }
}

__device__ inline void add8h(float* acc, uint4 p) {
    unsigned int w[4] = {p.x, p.y, p.z, p.w};
#pragma unroll
    for (int t = 0; t < 4; ++t) {
        __half2 h = *(const __half2*)&w[t];
        float2 f = __half22float2(h);
        acc[2 * t] += f.x;
        acc[2 * t + 1] += f.y;
    }
}

// Pull aggregation + norm + bias + tanh from fp16 Hs. F/8 lanes per dst node,
// 16 neighbor rows in flight per lane.
template <int F>
__global__ __launch_bounds__(256) void pull_agg_h(
    const int* __restrict__ row_start, const int* __restrict__ deg,
    const int* __restrict__ col, const __half* __restrict__ Hs,
    const float* __restrict__ dinv, const float* __restrict__ B,
    float* __restrict__ OUT, int n) {
    constexpr int TPE = F / 8;
    long long gid = (long long)blockIdx.x * 256 + threadIdx.x;
    int node = (int)(gid / TPE);
    int lane = (int)(gid % TPE);
    if (node >= n) return;
    const int beg = row_start[node];
    const int cnt = deg[node];
    const size_t lo = (size_t)lane * 8;

    float acc[8] = {0.f, 0.f, 0.f, 0.f, 0.f, 0.f, 0.f, 0.f};
    add8h(acc, *(const uint4*)(Hs + (size_t)node * F + lo));  // self term

    int j = 0;
    for (; j + 16 <= cnt; j += 16) {
        int s[16];
#pragma unroll
        for (int t = 0; t < 16; ++t) s[t] = col[beg + j + t];
        uint4 p[16];
#pragma unroll
        for (int t = 0; t < 16; ++t)
            p[t] = *(const uint4*)(Hs + (size_t)s[t] * F + lo);
#pragma unroll
        for (int t = 0; t < 16; ++t) add8h(acc, p[t]);
    }
    for (; j + 8 <= cnt; j += 8) {
        int s[8];
#pragma unroll
        for (int t = 0; t < 8; ++t) s[t] = col[beg + j + t];
        uint4 p[8];
#pragma unroll
        for (int t = 0; t < 8; ++t)
            p[t] = *(const uint4*)(Hs + (size_t)s[t] * F + lo);
#pragma unroll
        for (int t = 0; t < 8; ++t) add8h(acc, p[t]);
    }
    for (; j < cnt; ++j) {
        int s = col[beg + j];
        add8h(acc, *(const uint4*)(Hs + (size_t)s * F + lo));
    }

    float di = dinv[node];
    float4 b0 = *(const float4*)(B + lo);
    float4 b1 = *(const float4*)(B + lo + 4);
    float4 r0, r1;
    r0.x = tanhf(fmaf(acc[0], di, b0.x));
    r0.y = tanhf(fmaf(acc[1], di, b0.y));
    r0.z = tanhf(fmaf(acc[2], di, b0.z));
    r0.w = tanhf(fmaf(acc[3], di, b0.w));
    r1.x = tanhf(fmaf(acc[4], di, b1.x));
    r1.y = tanhf(fmaf(acc[5], di, b1.y));
    r1.z = tanhf(fmaf(acc[6], di, b1.z));
    r1.w = tanhf(fmaf(acc[7], di, b1.w));
    float* op = OUT + (size_t)node * F + lo;
    *(float4*)(op) = r0;
    *(float4*)(op + 4) = r1;
}

// Layer-3 pull (16 feats, table 3.2 MB) + fused classifier head.
__global__ __launch_bounds__(256) void pull_cls(
    const int* __restrict__ row_start, const int* __restrict__ deg,
    const int* __restrict__ col, const __half* __restrict__ Hs,
    const float* __restrict__ dinv, const float* __restrict__ B,
    const float* __restrict__ Wc, const float* __restrict__ bc,
    float* __restrict__ OUTH, float* __restrict__ OUTC, int n) {
    int gid = blockIdx.x * 256 + threadIdx.x;
    int node = gid >> 1;
    if (node >= n) return;
    const int half = gid & 1;
    const size_t lo = (size_t)half * 8;
    const int beg = row_start[node];
    const int cnt = deg[node];

    float acc[8] = {0.f, 0.f, 0.f, 0.f, 0.f, 0.f, 0.f, 0.f};
    add8h(acc, *(const uint4*)(Hs + (size_t)node * 16 + lo));  // self term

    int j = 0;
    for (; j + 16 <= cnt; j += 16) {
        int s[16];
#pragma unroll
        for (int t = 0; t < 16; ++t) s[t] = col[beg + j + t];
        uint4 p[16];
#pragma unroll
        for (int t = 0; t < 16; ++t)
            p[t] = *(const uint4*)(Hs + (size_t)s[t] * 16 + lo);
#pragma unroll
        for (int t = 0; t < 16; ++t) add8h(acc, p[t]);
    }
    for (; j + 8 <= cnt; j += 8) {
        int s[8];
#pragma unroll
        for (int t = 0; t < 8; ++t) s[t] = col[beg + j + t];
        uint4 p[8];
#pragma unroll
        for (int t = 0; t < 8; ++t)
            p[t] = *(const uint4*)(Hs + (size_t)s[t] * 16 + lo);
#pragma unroll
        for (int t = 0; t < 8; ++t) add8h(acc, p[t]);
    }
    for (; j < cnt; ++j) {
        int s = col[beg + j];
        add8h(acc, *(const uint4*)(Hs + (size_t)s * 16 + lo));
    }

    float di = dinv[node];
    float r[8];
#pragma unroll
    for (int k = 0; k < 8; ++k)
        r[k] = tanhf(fmaf(acc[k], di, B[lo + k]));

    float* op = OUTH + (size_t)node * 16 + lo;
    *(float4*)(op)     = make_float4(r[0], r[1], r[2], r[3]);
    *(float4*)(op + 4) = make_float4(r[4], r[5], r[6], r[7]);

    float o0 = 0.f, o1 = 0.f;
#pragma unroll
    for (int k = 0; k < 8; ++k) {
        o0 = fmaf(r[k], Wc[(lo + k) * 2 + 0], o0);
        o1 = fmaf(r[k], Wc[(lo + k) * 2 + 1], o1);
    }
    o0 += __shfl_xor(o0, 1);
    o1 += __shfl_xor(o1, 1);
    if (half == 0) {
        OUTC[(size_t)node * 2 + 0] = o0 + bc[0];
        OUTC[(size_t)node * 2 + 1] = o1 + bc[1];
    }
}

extern "C" void kernel_launch(void* const* d_in, const int* in_sizes, int n_in,
                              void* d_out, int out_size, void* d_ws, size_t ws_size,
                              hipStream_t stream) {
    const float* x  = (const float*)d_in[0];
    const int* ei   = (const int*)d_in[1];   // int32 (harness converts)
    const float* W1 = (const float*)d_in[2];
    const float* b1 = (const float*)d_in[3];
    const float* W2 = (const float*)d_in[4];
    const float* b2 = (const float*)d_in[5];
    const float* W3 = (const float*)d_in[6];
    const float* b3 = (const float*)d_in[7];
    const float* Wc = (const float*)d_in[8];
    const float* bc = (const float*)d_in[9];

    const int n = in_sizes[0] / 256;
    const int E = in_sizes[1] / 2;
    const int nbuc = (n + 255) >> BSHIFT;          // 391
    const int nch  = (E + EPB - 1) / EPB;          // 196
    const int NH   = nbuc * nch;                   // 76,636
    const int nb2  = (NH + 255) / 256;             // 300 <= 512

    float* outp = (float*)d_out;             // [n,2]
    float* outh = outp + (size_t)n * 2;      // [n,16]

    int*    deg       = (int*)d_ws;
    float*  dinv      = (float*)d_ws + (size_t)n;
    int*    row_start = (int*)d_ws + 2 * (size_t)n;
    int*    histG     = (int*)d_ws + 3 * (size_t)n;
    int*    incl      = histG + NH;
    int*    bsum      = incl + NH;
    int*    offs      = bsum + 512;
    int*    col       = offs + NH;
    __half* HsH       = (__half*)(col + E);  // row-major [n][FOUT]
    float*  xbuf      = (float*)(HsH + (size_t)n * 128);  // row-major f32
    unsigned int* ebuf = (unsigned int*)xbuf;  // alias: dead before pull writes

    // Packed-W buffers alias histG (NH*4 = 306 KB; dead after finalize_scan).
    unsigned short* Wpk1 = (unsigned short*)histG;
    unsigned short* Wpk2 = Wpk1 + (size_t)256 * 128 * 2;

    // --- atomic-free CSR build (shared by all 3 layers) ---
    hist_bucket<<<nch, 256, 0, stream>>>(ei, E, nbuc, nch, histG);
    scan_block<<<nb2, 256, 0, stream>>>(histG, NH, incl, bsum);
    scan_sums<<<1, 512, 0, stream>>>(bsum, nb2);
    finalize_scan<<<nb2, 256, 0, stream>>>(incl, bsum, histG, NH, offs);
    bucket_scatter<<<nch, 256, 0, stream>>>(ei, E, nbuc, nch, offs, ebuf);
    bucket_build<<<nbuc, 256, 0, stream>>>(ebuf, offs, E, nbuc, nch, n,
                                           col, deg, row_start, dinv);

    // --- pack W1/W2 into MFMA fragment order (histG dead by now) ---
    pack_w<256, 128><<<(256 / 32 * 128 / 16 * 512 + 255) / 256, 256, 0, stream>>>(W1, Wpk1);
    pack_w<128, 64><<<(128 / 32 * 64 / 16 * 512 + 255) / 256, 256, 0, stream>>>(W2, Wpk2);

    // --- layer 1: 256 -> 128 (MFMA, LDS-staged B) ---
    gemm_mfma<256, 128><<<(n + 127) / 128, 256, 0, stream>>>(x, Wpk1, dinv, HsH, n);
    pull_agg_h<128><<<(int)(((long long)n * 16 + 255) / 256), 256, 0, stream>>>(
        row_start, deg, col, HsH, dinv, b1, xbuf, n);

    // --- layer 2: 128 -> 64 (MFMA, LDS-staged B) ---
    gemm_mfma<128, 64><<<(n + 127) / 128, 256, 0, stream>>>(xbuf, Wpk2, dinv, HsH, n);
    pull_agg_h<64><<<(int)(((long long)n * 8 + 255) / 256), 256, 0, stream>>>(
        row_start, deg, col, HsH, dinv, b2, xbuf, n);

    // --- layer 3: 64 -> 16 (f32 path) + fused classifier pull ---
    gemm_tile_h<64, 16, 256><<<(n + 255) / 256, 256, 0, stream>>>(xbuf, W3, dinv, HsH, n);
    pull_cls<<<(2 * n + 255) / 256, 256, 0, stream>>>(row_start, deg, col, HsH,
                                                      dinv, b3, Wc, bc, outh, outp, n);
}